// Round 9
// baseline (342.536 us; speedup 1.0000x reference)
//
#include <hip/hip_runtime.h>
#include <math.h>

#define NN 100000
#define NE 1600000
#define F_IN 128
#define C 128           // N_HEADS * F_OUT
#define NEG_SLOPE 0.2f
#define SCAN_NB ((NN + 1023) / 1024)   // 98
#define PROJ_NB ((NN + 63) / 64)       // 1563
#define HIST_GB 1024                   // hist grid-stride blocks

typedef __attribute__((ext_vector_type(8))) short short8;    // 8 x bf16
typedef __attribute__((ext_vector_type(4))) float f32x4;
typedef __attribute__((ext_vector_type(4))) float floatx4;
typedef __attribute__((ext_vector_type(4))) unsigned short ushortx4;

static __device__ __forceinline__ unsigned short f2bf(float f) {
    unsigned int u = __float_as_uint(f);
    unsigned int r = (u + 0x7fff + ((u >> 16) & 1)) >> 16;  // RNE
    return (unsigned short)r;
}
static __device__ __forceinline__ float bf2f(unsigned short h) {
    return __uint_as_float((unsigned int)h << 16);
}

// ---------------------------------------------------------------------------
// Btf: fragment-major B for mfma_f32_16x16x32_bf16.
// Btf[((nt*4+kc)*64 + lane)*8 + j] = B[k][n], n = nt*16+(lane&15),
//   k = kc*32 + (lane>>4)*8 + j.  n<128 -> W, else W_res.
// ---------------------------------------------------------------------------
__global__ __launch_bounds__(256)
void wconv_kernel(const float* __restrict__ W,
                  const float* __restrict__ Wr,
                  unsigned short* __restrict__ Btf)
{
    int g = blockIdx.x * 256 + threadIdx.x;   // 0..4095
    int nt = g >> 8;
    int kc = (g >> 6) & 3;
    int l  = g & 63;
    int n  = nt * 16 + (l & 15);
    int kb = kc * 32 + (l >> 4) * 8;
    unsigned short v[8];
    #pragma unroll
    for (int j = 0; j < 8; ++j) {
        int k = kb + j;
        float f = (n < 128) ? W[(size_t)k * 128 + n] : Wr[(size_t)k * 128 + (n - 128)];
        v[j] = f2bf(f);
    }
    *(short8*)&Btf[(size_t)g * 8] = *(short8*)v;
}

// ---------------------------------------------------------------------------
// Fat kernel. blocks >= PROJ_NB: grid-stride histogram (independent atomics
// per iteration -> ILP across atomic latency).
// blocks < PROJ_NB: projection. Wave w owns cols [64w,64w+64) for all 64
// rows; B-fragments in registers from L2 (no B staging, no extra barriers).
// LDS 19.5KB: As[64][136] bf16, T2 overlays As after MFMA barrier.
// ---------------------------------------------------------------------------
__global__ __launch_bounds__(256)
void proj_hist_kernel(const float* __restrict__ feat,
                      const unsigned short* __restrict__ Btf,
                      const float* __restrict__ att_src,
                      const float* __restrict__ att_dst,
                      const int* __restrict__ dst,
                      unsigned short* __restrict__ xb,
                      unsigned short* __restrict__ resb,
                      float* __restrict__ a_s,
                      float* __restrict__ a_d,
                      int* __restrict__ deg,
                      int* __restrict__ rank)
{
    __shared__ __align__(16) char smem[17408];
    __shared__ float s_as[64][4];
    __shared__ float s_ad[64][4];
    const int tid = threadIdx.x;

    if (blockIdx.x >= PROJ_NB) {          // ---- histogram (grid-stride) ----
        const int stride = HIST_GB * 256;
        for (int e = (blockIdx.x - PROJ_NB) * 256 + tid; e < NE; e += stride)
            rank[e] = atomicAdd(&deg[dst[e]], 1);
        return;
    }

    unsigned short* As = (unsigned short*)smem;   // [64][136]
    const int base = blockIdx.x * 64;

    // stage A: 64 rows x 128 cols fp32 -> bf16 LDS
    #pragma unroll
    for (int it = 0; it < 8; ++it) {
        int idx = it * 256 + tid;
        int row = idx >> 5;
        int c4  = idx & 31;
        int n = base + row;
        if (n < NN) {
            floatx4 f = __builtin_nontemporal_load(
                (const floatx4*)&feat[(size_t)n * F_IN + c4 * 4]);
            ushortx4 h;
            h.x = f2bf(f.x); h.y = f2bf(f.y); h.z = f2bf(f.z); h.w = f2bf(f.w);
            *(ushortx4*)&As[row * 136 + c4 * 4] = h;
        }
    }
    __syncthreads();

    const int l = tid & 63;
    const int w = tid >> 6;
    const int quad = l >> 4;
    const int lo16 = l & 15;

    f32x4 acc[4][4];   // [rt][ntl]
    #pragma unroll
    for (int rt = 0; rt < 4; ++rt)
        #pragma unroll
        for (int ntl = 0; ntl < 4; ++ntl)
            acc[rt][ntl] = (f32x4){0.f, 0.f, 0.f, 0.f};

    #pragma unroll
    for (int ntl = 0; ntl < 4; ++ntl) {
        // wave's nt = w*4 + ntl; 4 kc fragments, 1KB coalesced each
        const unsigned short* bb = &Btf[(size_t)((w * 4 + ntl) * 4) * 512 + l * 8];
        short8 b0 = *(const short8*)&bb[0];
        short8 b1 = *(const short8*)&bb[512];
        short8 b2 = *(const short8*)&bb[1024];
        short8 b3 = *(const short8*)&bb[1536];
        #pragma unroll
        for (int rt = 0; rt < 4; ++rt) {
            const unsigned short* ap = &As[(rt * 16 + lo16) * 136 + quad * 8];
            short8 a0 = *(const short8*)&ap[0];
            short8 a1 = *(const short8*)&ap[32];
            short8 a2 = *(const short8*)&ap[64];
            short8 a3 = *(const short8*)&ap[96];
            acc[rt][ntl] = __builtin_amdgcn_mfma_f32_16x16x32_bf16(a0, b0, acc[rt][ntl], 0, 0, 0);
            acc[rt][ntl] = __builtin_amdgcn_mfma_f32_16x16x32_bf16(a1, b1, acc[rt][ntl], 0, 0, 0);
            acc[rt][ntl] = __builtin_amdgcn_mfma_f32_16x16x32_bf16(a2, b2, acc[rt][ntl], 0, 0, 0);
            acc[rt][ntl] = __builtin_amdgcn_mfma_f32_16x16x32_bf16(a3, b3, acc[rt][ntl], 0, 0, 0);
        }
    }
    __syncthreads();   // As dead; per-wave T2 overlays it

    float* T2 = (float*)smem + w * (16 * 68);   // wave-private [16][68]
    const int cidx = (w & 1) * 64 + lo16 * 4;   // col block for logits weights
    floatx4 ws4 = *(const floatx4*)&att_src[cidx];
    floatx4 wd4 = *(const floatx4*)&att_dst[cidx];

    #pragma unroll
    for (int rt = 0; rt < 4; ++rt) {
        #pragma unroll
        for (int ntl = 0; ntl < 4; ++ntl)
            #pragma unroll
            for (int r = 0; r < 4; ++r)
                T2[(quad * 4 + r) * 68 + ntl * 16 + lo16] = acc[rt][ntl][r];
        #pragma unroll
        for (int it = 0; it < 4; ++it) {
            int rloc = it * 4 + quad;
            int node = base + rt * 16 + rloc;
            floatx4 v = *(floatx4*)&T2[rloc * 68 + lo16 * 4];
            ushortx4 hh;
            hh.x = f2bf(v.x); hh.y = f2bf(v.y); hh.z = f2bf(v.z); hh.w = f2bf(v.w);
            if (node < NN) {
                if (w < 2)
                    __builtin_nontemporal_store(hh,
                        (ushortx4*)&xb[(size_t)node * C + w * 64 + lo16 * 4]);
                else
                    __builtin_nontemporal_store(hh,
                        (ushortx4*)&resb[(size_t)node * C + (w - 2) * 64 + lo16 * 4]);
            }
            if (w < 2) {
                float ps = v.x * ws4.x + v.y * ws4.y + v.z * ws4.z + v.w * ws4.w;
                float pd = v.x * wd4.x + v.y * wd4.y + v.z * wd4.z + v.w * wd4.w;
                #pragma unroll
                for (int d = 1; d < 8; d <<= 1) {
                    ps += __shfl_xor(ps, d, 64);
                    pd += __shfl_xor(pd, d, 64);
                }
                if ((l & 7) == 0) {
                    int hd = w * 2 + (lo16 >> 3);
                    s_as[rt * 16 + rloc][hd] = ps;
                    s_ad[rt * 16 + rloc][hd] = pd;
                }
            }
        }
    }

    // coalesced logits store: one contiguous 1KB store per array
    __syncthreads();
    int idx = base * 4 + tid;
    if (idx < NN * 4) {
        a_s[idx] = ((float*)s_as)[tid];
        a_d[idx] = ((float*)s_ad)[tid];
    }
}

// ---------------------------------------------------------------------------
// multi-block exclusive scan
// ---------------------------------------------------------------------------
__global__ __launch_bounds__(1024)
void scan1_kernel(const int* __restrict__ deg, int* __restrict__ row_ptr,
                  int* __restrict__ bsum)
{
    __shared__ int wsum[16];
    const int t = threadIdx.x, lane = t & 63, wid = t >> 6;
    const int i = blockIdx.x * 1024 + t;
    int v0 = (i < NN) ? deg[i] : 0;
    int v = v0;
    #pragma unroll
    for (int off = 1; off < 64; off <<= 1) {
        int u = __shfl_up(v, off, 64);
        if (lane >= off) v += u;
    }
    if (lane == 63) wsum[wid] = v;
    __syncthreads();
    if (t == 0) {
        int run = 0;
        #pragma unroll
        for (int s = 0; s < 16; ++s) { int tmp = wsum[s]; wsum[s] = run; run += tmp; }
        bsum[blockIdx.x] = run;
    }
    __syncthreads();
    if (i < NN) row_ptr[i] = wsum[wid] + (v - v0);
}

__global__ __launch_bounds__(128)
void scan2_kernel(int* __restrict__ bsum)
{
    __shared__ int w0;
    const int t = threadIdx.x, lane = t & 63;
    int v0 = (t < SCAN_NB) ? bsum[t] : 0;
    int v = v0;
    #pragma unroll
    for (int off = 1; off < 64; off <<= 1) {
        int u = __shfl_up(v, off, 64);
        if (lane >= off) v += u;
    }
    if (t == 63) w0 = v;
    __syncthreads();
    int excl = (v - v0) + ((t >= 64) ? w0 : 0);
    if (t < SCAN_NB) bsum[t] = excl;
}

__global__ __launch_bounds__(1024)
void scan3_kernel(int* __restrict__ row_ptr, const int* __restrict__ bsum)
{
    const int i = blockIdx.x * 1024 + threadIdx.x;
    if (i < NN) row_ptr[i] = row_ptr[i] + bsum[i >> 10];
    if (i == 0) row_ptr[NN] = NE;
}

// ---------------------------------------------------------------------------
// scatter: pure load->store, no atomics (plain store: let L2 write-combine)
// ---------------------------------------------------------------------------
__global__ void scatter_kernel(const int* __restrict__ src,
                               const int* __restrict__ dst,
                               const int* __restrict__ rank,
                               const int* __restrict__ row_ptr,
                               int* __restrict__ csr_src)
{
    int e = blockIdx.x * blockDim.x + threadIdx.x;
    if (e < NE)
        csr_src[row_ptr[dst[e]] + rank[e]] = src[e];
}

// ---------------------------------------------------------------------------
// aggregation: one wave per dst node, single pass (unchanged from round 8)
// ---------------------------------------------------------------------------
__global__ __launch_bounds__(256)
void agg_kernel(const unsigned short* __restrict__ xb,
                const unsigned short* __restrict__ resb,
                const float* __restrict__ a_s,
                const float* __restrict__ a_d,
                const int* __restrict__ row_ptr,
                const int* __restrict__ csr_src,
                float* __restrict__ out)
{
    __shared__ float s_alpha[4][64 * 4];
    __shared__ int   s_srcs[4][64];
    const int tid = threadIdx.x;
    const int w = tid >> 6;
    const int l = tid & 63;
    const int n = blockIdx.x * 4 + w;
    if (n >= NN) return;
    const int r0  = row_ptr[n];
    const int deg = row_ptr[n + 1] - r0;

    const int half = l >> 5;
    const int hl   = l & 31;
    const int h    = hl >> 3;

    if (deg == 0) {                      // out = residual only
        if (half == 0) {
            ushort4 rv = *(const ushort4*)&resb[(size_t)n * C + hl * 4];
            floatx4 o;
            o.x = bf2f(rv.x); o.y = bf2f(rv.y);
            o.z = bf2f(rv.z); o.w = bf2f(rv.w);
            __builtin_nontemporal_store(o, (floatx4*)&out[(size_t)n * C + hl * 4]);
        }
        return;
    }

    const float4 ad4 = *(const float4*)&a_d[n * 4];

    float ax = 0.f, ay = 0.f, az = 0.f, aw = 0.f;
    float dx = 0.f, dy = 0.f, dz = 0.f, dw = 0.f;

    for (int c0 = 0; c0 < deg; c0 += 64) {
        int e = c0 + l;
        int s = 0;
        float4 ex = {0.f, 0.f, 0.f, 0.f};
        if (e < deg) {
            s = csr_src[r0 + e];
            float4 as4 = *(const float4*)&a_s[s * 4];
            float e0 = as4.x + ad4.x, e1 = as4.y + ad4.y;
            float e2 = as4.z + ad4.z, e3 = as4.w + ad4.w;
            e0 = (e0 > 0.f) ? e0 : NEG_SLOPE * e0;
            e1 = (e1 > 0.f) ? e1 : NEG_SLOPE * e1;
            e2 = (e2 > 0.f) ? e2 : NEG_SLOPE * e2;
            e3 = (e3 > 0.f) ? e3 : NEG_SLOPE * e3;
            ex.x = __expf(e0); ex.y = __expf(e1);
            ex.z = __expf(e2); ex.w = __expf(e3);
            dx += ex.x; dy += ex.y; dz += ex.z; dw += ex.w;
        }
        s_srcs[w][l] = s;
        *(float4*)&s_alpha[w][l * 4] = ex;   // wave-private; DS in-order

        int cn = min(64, deg - c0);
        int iters = (cn + 1) >> 1;
        #pragma unroll 2
        for (int i = 0; i < iters; ++i) {
            int ii = i * 2 + half;
            int   si = s_srcs[w][ii];
            float al = s_alpha[w][ii * 4 + h];
            ushort4 uv = *(const ushort4*)&xb[(size_t)si * C + hl * 4];
            ax = fmaf(al, bf2f(uv.x), ax);
            ay = fmaf(al, bf2f(uv.y), ay);
            az = fmaf(al, bf2f(uv.z), az);
            aw = fmaf(al, bf2f(uv.w), aw);
        }
    }

    #pragma unroll
    for (int d = 32; d > 0; d >>= 1) {
        dx += __shfl_xor(dx, d, 64);
        dy += __shfl_xor(dy, d, 64);
        dz += __shfl_xor(dz, d, 64);
        dw += __shfl_xor(dw, d, 64);
    }
    float den = (h == 0) ? dx : (h == 1) ? dy : (h == 2) ? dz : dw;
    float inv = 1.f / den;

    ax += __shfl_xor(ax, 32, 64);
    ay += __shfl_xor(ay, 32, 64);
    az += __shfl_xor(az, 32, 64);
    aw += __shfl_xor(aw, 32, 64);

    if (half == 0) {
        ushort4 rv = *(const ushort4*)&resb[(size_t)n * C + hl * 4];
        floatx4 o;
        o.x = bf2f(rv.x) + ax * inv;
        o.y = bf2f(rv.y) + ay * inv;
        o.z = bf2f(rv.z) + az * inv;
        o.w = bf2f(rv.w) + aw * inv;
        __builtin_nontemporal_store(o, (floatx4*)&out[(size_t)n * C + hl * 4]);
    }
}

// ---------------------------------------------------------------------------
extern "C" void kernel_launch(void* const* d_in, const int* in_sizes, int n_in,
                              void* d_out, int out_size, void* d_ws, size_t ws_size,
                              hipStream_t stream)
{
    const float* feat    = (const float*)d_in[0];
    const float* W       = (const float*)d_in[1];
    const float* att_src = (const float*)d_in[2];
    const float* att_dst = (const float*)d_in[3];
    const float* W_res   = (const float*)d_in[4];
    const int*   src     = (const int*)d_in[5];
    const int*   dst     = (const int*)d_in[6];
    float* out = (float*)d_out;

    char* p = (char*)d_ws;
    unsigned short* xb   = (unsigned short*)p; p += (size_t)NN * C * sizeof(unsigned short);
    unsigned short* resb = (unsigned short*)p; p += (size_t)NN * C * sizeof(unsigned short);
    unsigned short* Btf  = (unsigned short*)p; p += (size_t)256 * 128 * sizeof(unsigned short);
    float* a_s = (float*)p;            p += (size_t)NN * 4 * sizeof(float);
    float* a_d = (float*)p;            p += (size_t)NN * 4 * sizeof(float);
    int* deg     = (int*)p;            p += (size_t)NN * sizeof(int);
    int* row_ptr = (int*)p;            p += (size_t)(NN + 1) * sizeof(int);
    int* bsum    = (int*)p;            p += (size_t)256 * sizeof(int);
    int* rank    = (int*)p;            p += (size_t)NE * sizeof(int);
    int* csr_src = (int*)p;            p += (size_t)NE * sizeof(int);

    hipMemsetAsync(deg, 0, (size_t)NN * sizeof(int), stream);

    wconv_kernel<<<16, 256, 0, stream>>>(W, W_res, Btf);
    proj_hist_kernel<<<PROJ_NB + HIST_GB, 256, 0, stream>>>(
        feat, Btf, att_src, att_dst, dst, xb, resb, a_s, a_d, deg, rank);
    scan1_kernel<<<SCAN_NB, 1024, 0, stream>>>(deg, row_ptr, bsum);
    scan2_kernel<<<1, 128, 0, stream>>>(bsum);
    scan3_kernel<<<SCAN_NB, 1024, 0, stream>>>(row_ptr, bsum);
    scatter_kernel<<<(NE + 255) / 256, 256, 0, stream>>>(src, dst, rank, row_ptr, csr_src);
    agg_kernel<<<(NN + 3) / 4, 256, 0, stream>>>(xb, resb, a_s, a_d, row_ptr, csr_src, out);
}